// Round 4
// baseline (191.958 us; speedup 1.0000x reference)
//
#include <hip/hip_runtime.h>
#include <math.h>

#define EPS 1e-8f

constexpr int B_ = 128;     // batch
constexpr int Q_ = 20;      // queries per sample
constexpr int D_ = 11;      // feature dim
constexpr int N_ = 100000;  // songs
constexpr int DP_ = 12;     // padded feature dim (3x float4)
constexpr int NPAIR = B_ * Q_;  // 2560
constexpr int STPB = 128;   // sim kernel block size
constexpr int PPT = 4;      // pairs per thread

// ---------------- fused prep: MLP encoder + song pre-normalization ---------------
// blocks [0, B_)            : MLP for batch b -> pnorm[b*Q ... ] (normalized, padded)
// blocks [B_, B_+ceil(N/256)): snorm rows     -> snorm[N][12]
__global__ void prep_kernel(const float* __restrict__ x,
                            const float* __restrict__ W1, const float* __restrict__ b1,
                            const float* __restrict__ W2, const float* __restrict__ b2,
                            const float* __restrict__ W3, const float* __restrict__ b3,
                            const float* __restrict__ songs,
                            float* __restrict__ pnorm, float* __restrict__ snorm,
                            int do_snorm)
{
    const int t = threadIdx.x;
    if (blockIdx.x >= B_) {
        if (!do_snorm) return;
        const int i = (blockIdx.x - B_) * blockDim.x + t;
        if (i >= N_) return;
        float v[DP_]; float ss = 0.0f;
#pragma unroll
        for (int d = 0; d < D_; ++d) { v[d] = songs[(size_t)i * D_ + d]; ss += v[d] * v[d]; }
        float nrm = fmaxf(sqrtf(ss), EPS);
#pragma unroll
        for (int d = 0; d < D_; ++d) v[d] /= nrm;
        v[D_] = 0.0f;
        float4* o = reinterpret_cast<float4*>(snorm + (size_t)i * DP_);
        o[0] = make_float4(v[0], v[1], v[2], v[3]);
        o[1] = make_float4(v[4], v[5], v[6], v[7]);
        o[2] = make_float4(v[8], v[9], v[10], v[11]);
        return;
    }
    __shared__ float xr[55];
    __shared__ float h1[128];
    __shared__ float h2[64];
    __shared__ float prod[220];
    const int b = blockIdx.x;
    if (t < 55) xr[t] = x[b * 55 + t];
    __syncthreads();
    if (t < 128) {
        float s = b1[t];
        for (int k = 0; k < 55; ++k) s += xr[k] * W1[k * 128 + t];
        h1[t] = fmaxf(s, 0.0f);
    }
    __syncthreads();
    if (t < 64) {
        float s = b2[t];
        for (int k = 0; k < 128; ++k) s += h1[k] * W2[k * 64 + t];
        h2[t] = fmaxf(s, 0.0f);
    }
    __syncthreads();
    if (t < 220) {
        float s = b3[t];
        for (int k = 0; k < 64; ++k) s += h2[k] * W3[k * 220 + t];
        prod[t] = s;
    }
    __syncthreads();
    if (t < Q_) {
        float ss = 0.0f;
        for (int d = 0; d < D_; ++d) { float v = prod[t * D_ + d]; ss += v * v; }
        float nrm = fmaxf(sqrtf(ss), EPS);
        float* o = pnorm + (b * Q_ + t) * DP_;
        for (int d = 0; d < D_; ++d) o[d] = prod[t * D_ + d] / nrm;
        o[D_] = 0.0f;
    }
}

// dot over 11 dims, fixed fmaf sequence (deterministic, identical at every call site)
__device__ __forceinline__ float dot11(const float* __restrict__ q,
                                       const float4 a, const float4 b, const float4 c)
{
    float x = q[0] * a.x;
    x = fmaf(q[1], a.y, x);
    x = fmaf(q[2], a.z, x);
    x = fmaf(q[3], a.w, x);
    x = fmaf(q[4], b.x, x);
    x = fmaf(q[5], b.y, x);
    x = fmaf(q[6], b.z, x);
    x = fmaf(q[7], b.w, x);
    x = fmaf(q[8], c.x, x);
    x = fmaf(q[9], c.y, x);
    x = fmaf(q[10], c.z, x);
    return x;
}

__device__ __forceinline__ void loadg(const float4* __restrict__ s4, int g, float4 buf[12])
{
#pragma unroll
    for (int k = 0; k < 12; ++k) buf[k] = s4[(size_t)g * 12 + k];
}

__device__ __forceinline__ void computeg(const float qv[PPT][D_], const float4 buf[12],
                                         float bv[PPT], int gi[PPT], int g)
{
#pragma unroll
    for (int p = 0; p < PPT; ++p) {
        float a0 = dot11(qv[p], buf[0], buf[1],  buf[2]);
        float a1 = dot11(qv[p], buf[3], buf[4],  buf[5]);
        float a2 = dot11(qv[p], buf[6], buf[7],  buf[8]);
        float a3 = dot11(qv[p], buf[9], buf[10], buf[11]);
        float m = fmaxf(fmaxf(a0, a1), fmaxf(a2, a3));   // fuses to v_max3 + v_max
        // strictly-greater keeps FIRST group: numpy first-index argmax semantics
        if (m > bv[p]) { bv[p] = m; gi[p] = g; }
    }
}

// ---------------- sim + per-chunk argmax: 4 pairs/thread, SW-pipelined loads ------
// grid = (NCH, NPAIR/(PPT*STPB)). Song addresses wave-uniform; explicit double
// buffer (A/B alternation, no copies) keeps next group's 12 float4 loads in
// flight under the current group's 176 FMAs.
template<int NCH>
__global__ __launch_bounds__(STPB, 2)
void sim4_kernel(const float* __restrict__ pnorm,
                 const float* __restrict__ snorm,
                 float* __restrict__ pval, int* __restrict__ pidx)
{
    constexpr int CS = N_ / NCH;   // songs per chunk (400 for NCH=250)
    constexpr int NG = CS / 4;     // 4-song groups per chunk (100) -- even
    const int chunk = blockIdx.x;
    const int t = threadIdx.x;
    const int jbase = blockIdx.y * (PPT * STPB) + t;

    float qv[PPT][D_];
#pragma unroll
    for (int p = 0; p < PPT; ++p)
#pragma unroll
        for (int d = 0; d < D_; ++d) qv[p][d] = pnorm[(jbase + p * STPB) * DP_ + d];

    float bv[PPT]; int gi[PPT];
#pragma unroll
    for (int p = 0; p < PPT; ++p) { bv[p] = -1e30f; gi[p] = 0; }

    const float4* s4 = reinterpret_cast<const float4*>(snorm) + (size_t)chunk * CS * 3;

    float4 A[12], Bv[12];
    loadg(s4, 0, A);
    for (int g = 0; g < NG; g += 2) {
        loadg(s4, g + 1, Bv);                 // prefetch odd group
        computeg(qv, A, bv, gi, g);
        if (g + 2 < NG) loadg(s4, g + 2, A);  // prefetch next even group
        computeg(qv, Bv, bv, gi, g + 1);
    }

    // Recompute winning group with the identical fmaf sequence -> bit-exact match;
    // reverse scan picks the FIRST in-group index achieving the max.
#pragma unroll
    for (int p = 0; p < PPT; ++p) {
        const float4* vg = s4 + (size_t)gi[p] * 12;
        float4 w[12];
#pragma unroll
        for (int k = 0; k < 12; ++k) w[k] = vg[k];
        float a0 = dot11(qv[p], w[0], w[1],  w[2]);
        float a1 = dot11(qv[p], w[3], w[4],  w[5]);
        float a2 = dot11(qv[p], w[6], w[7],  w[8]);
        float a3 = dot11(qv[p], w[9], w[10], w[11]);
        int r = chunk * CS + gi[p] * 4;
        int idx = r;
        if (a3 == bv[p]) idx = r + 3;
        if (a2 == bv[p]) idx = r + 2;
        if (a1 == bv[p]) idx = r + 1;
        if (a0 == bv[p]) idx = r;
        const int j = jbase + p * STPB;
        // [chunk][pair] layout: adjacent lanes -> adjacent addresses (full lines)
        pval[(size_t)chunk * NPAIR + j] = bv[p];
        pidx[(size_t)chunk * NPAIR + j] = idx;
    }
}

// ---------------- fallback (no snorm workspace): normalize on the fly ------------
template<int NCH>
__global__ void sim2f_kernel(const float* __restrict__ pnorm,
                             const float* __restrict__ songs,
                             float* __restrict__ pval, int* __restrict__ pidx)
{
    constexpr int CS = N_ / NCH;
    const int chunk = blockIdx.x;
    const int j = blockIdx.y * 256 + threadIdx.x;

    float qv[D_];
#pragma unroll
    for (int d = 0; d < D_; ++d) qv[d] = pnorm[j * DP_ + d];

    float bestv = -1e30f;
    int   besti = 0;
    const int base = chunk * CS;
    for (int i = base; i < base + CS; ++i) {
        float sv[D_]; float ss = 0.0f;
#pragma unroll
        for (int d = 0; d < D_; ++d) { sv[d] = songs[(size_t)i * D_ + d]; ss += sv[d] * sv[d]; }
        float nrm = fmaxf(sqrtf(ss), EPS);
        float a = qv[0] * (sv[0] / nrm);
#pragma unroll
        for (int d = 1; d < D_; ++d) a = fmaf(qv[d], sv[d] / nrm, a);
        if (a > bestv) { bestv = a; besti = i; }
    }
    pval[(size_t)chunk * NPAIR + j] = bestv;
    pidx[(size_t)chunk * NPAIR + j] = besti;
}

// ---------------- final reduce over chunks + gather: one wave per pair ------------
template<int NCH>
__global__ void final2_kernel(const float* __restrict__ pval, const int* __restrict__ pidx,
                              const float* __restrict__ songs, float* __restrict__ out)
{
    const int pair = blockIdx.x * 4 + (threadIdx.x >> 6);
    const int lane = threadIdx.x & 63;
    float v = -1e30f; int ix = 0x7fffffff;
#pragma unroll
    for (int k = 0; k < (NCH + 63) / 64; ++k) {
        int c = lane + k * 64;
        if (c < NCH) {
            float v2 = pval[(size_t)c * NPAIR + pair];
            int   i2 = pidx[(size_t)c * NPAIR + pair];
            if (v2 > v || (v2 == v && i2 < ix)) { v = v2; ix = i2; }
        }
    }
#pragma unroll
    for (int off = 1; off < 64; off <<= 1) {
        float v2 = __shfl_xor(v, off, 64);
        int   i2 = __shfl_xor(ix, off, 64);
        if (v2 > v || (v2 == v && i2 < ix)) { v = v2; ix = i2; }
    }
    if (lane < D_) out[(size_t)pair * D_ + lane] = songs[(size_t)ix * D_ + lane];
}

extern "C" void kernel_launch(void* const* d_in, const int* in_sizes, int n_in,
                              void* d_out, int out_size, void* d_ws, size_t ws_size,
                              hipStream_t stream)
{
    const float* x     = (const float*)d_in[0];
    const float* W1    = (const float*)d_in[1];
    const float* b1    = (const float*)d_in[2];
    const float* W2    = (const float*)d_in[3];
    const float* b2    = (const float*)d_in[4];
    const float* W3    = (const float*)d_in[5];
    const float* b3    = (const float*)d_in[6];
    const float* songs = (const float*)d_in[7];
    float* out = (float*)d_out;

    float* pnorm = (float*)d_ws;                            // NPAIR*DP floats
    constexpr size_t PN = (size_t)NPAIR * DP_;
    constexpr size_t SN = (size_t)N_ * DP_;
    constexpr int NCH = 250;
    constexpr int SNB = (N_ + 255) / 256;                   // snorm blocks

    const size_t need_full = (PN + SN + 2ull * NPAIR * NCH) * sizeof(float);
    const size_t need_mid  = (PN + 2ull * NPAIR * NCH) * sizeof(float);

    if (ws_size >= need_full) {
        float* snorm = pnorm + PN;
        float* pval  = snorm + SN;
        int*   pidx  = (int*)(pval + (size_t)NPAIR * NCH);
        prep_kernel<<<B_ + SNB, 256, 0, stream>>>(x, W1, b1, W2, b2, W3, b3, songs,
                                                  pnorm, snorm, 1);
        sim4_kernel<NCH><<<dim3(NCH, NPAIR / (PPT * STPB)), STPB, 0, stream>>>(
            pnorm, snorm, pval, pidx);
        final2_kernel<NCH><<<NPAIR / 4, 256, 0, stream>>>(pval, pidx, songs, out);
    } else if (ws_size >= need_mid) {
        float* pval = pnorm + PN;
        int*   pidx = (int*)(pval + (size_t)NPAIR * NCH);
        prep_kernel<<<B_, 256, 0, stream>>>(x, W1, b1, W2, b2, W3, b3, songs,
                                            pnorm, nullptr, 0);
        sim2f_kernel<NCH><<<dim3(NCH, NPAIR / 256), 256, 0, stream>>>(pnorm, songs, pval, pidx);
        final2_kernel<NCH><<<NPAIR / 4, 256, 0, stream>>>(pval, pidx, songs, out);
    } else {
        constexpr int NCH2 = 50;
        float* pval = pnorm + PN;
        int*   pidx = (int*)(pval + (size_t)NPAIR * NCH2);
        prep_kernel<<<B_, 256, 0, stream>>>(x, W1, b1, W2, b2, W3, b3, songs,
                                            pnorm, nullptr, 0);
        sim2f_kernel<NCH2><<<dim3(NCH2, NPAIR / 256), 256, 0, stream>>>(pnorm, songs, pval, pidx);
        final2_kernel<NCH2><<<NPAIR / 4, 256, 0, stream>>>(pval, pidx, songs, out);
    }
}

// Round 5
// 145.780 us; speedup vs baseline: 1.3168x; 1.3168x over previous
//
#include <hip/hip_runtime.h>
#include <math.h>

#define EPS 1e-8f

constexpr int B_ = 128;     // batch
constexpr int Q_ = 20;      // queries per sample
constexpr int D_ = 11;      // feature dim
constexpr int N_ = 100000;  // songs
constexpr int DP_ = 12;     // padded feature dim (3x float4)
constexpr int NPAIR = B_ * Q_;  // 2560
constexpr int TPB = 256;
constexpr int REP = NPAIR / (2 * TPB);  // 5 pair-blocks (2 pairs per thread)

// ---------------- fused prep: MLP encoder + song pre-normalization ---------------
__global__ void prep_kernel(const float* __restrict__ x,
                            const float* __restrict__ W1, const float* __restrict__ b1,
                            const float* __restrict__ W2, const float* __restrict__ b2,
                            const float* __restrict__ W3, const float* __restrict__ b3,
                            const float* __restrict__ songs,
                            float* __restrict__ pnorm, float* __restrict__ snorm,
                            int do_snorm)
{
    const int t = threadIdx.x;
    if (blockIdx.x >= B_) {
        if (!do_snorm) return;
        const int i = (blockIdx.x - B_) * blockDim.x + t;
        if (i >= N_) return;
        float v[DP_]; float ss = 0.0f;
#pragma unroll
        for (int d = 0; d < D_; ++d) { v[d] = songs[(size_t)i * D_ + d]; ss += v[d] * v[d]; }
        float nrm = fmaxf(sqrtf(ss), EPS);
#pragma unroll
        for (int d = 0; d < D_; ++d) v[d] /= nrm;
        v[D_] = 0.0f;
        float4* o = reinterpret_cast<float4*>(snorm + (size_t)i * DP_);
        o[0] = make_float4(v[0], v[1], v[2], v[3]);
        o[1] = make_float4(v[4], v[5], v[6], v[7]);
        o[2] = make_float4(v[8], v[9], v[10], v[11]);
        return;
    }
    __shared__ float xr[55];
    __shared__ float h1[128];
    __shared__ float h2[64];
    __shared__ float prod[220];
    const int b = blockIdx.x;
    if (t < 55) xr[t] = x[b * 55 + t];
    __syncthreads();
    if (t < 128) {
        float s = b1[t];
        for (int k = 0; k < 55; ++k) s += xr[k] * W1[k * 128 + t];
        h1[t] = fmaxf(s, 0.0f);
    }
    __syncthreads();
    if (t < 64) {
        float s = b2[t];
        for (int k = 0; k < 128; ++k) s += h1[k] * W2[k * 64 + t];
        h2[t] = fmaxf(s, 0.0f);
    }
    __syncthreads();
    if (t < 220) {
        float s = b3[t];
        for (int k = 0; k < 64; ++k) s += h2[k] * W3[k * 220 + t];
        prod[t] = s;
    }
    __syncthreads();
    if (t < Q_) {
        float ss = 0.0f;
        for (int d = 0; d < D_; ++d) { float v = prod[t * D_ + d]; ss += v * v; }
        float nrm = fmaxf(sqrtf(ss), EPS);
        float* o = pnorm + (b * Q_ + t) * DP_;
        for (int d = 0; d < D_; ++d) o[d] = prod[t * D_ + d] / nrm;
        o[D_] = 0.0f;
    }
}

// dot over 11 dims, fixed fmaf sequence (deterministic, identical at every call site)
__device__ __forceinline__ float dot11(const float* __restrict__ q,
                                       const float4 a, const float4 b, const float4 c)
{
    float x = q[0] * a.x;
    x = fmaf(q[1], a.y, x);
    x = fmaf(q[2], a.z, x);
    x = fmaf(q[3], a.w, x);
    x = fmaf(q[4], b.x, x);
    x = fmaf(q[5], b.y, x);
    x = fmaf(q[6], b.z, x);
    x = fmaf(q[7], b.w, x);
    x = fmaf(q[8], c.x, x);
    x = fmaf(q[9], c.y, x);
    x = fmaf(q[10], c.z, x);
    return x;
}

// ---------------- sim + per-chunk argmax: 2 pairs/thread, XCD-swizzled 1-D grid ---
// bid -> (u = bid%8 (the XCD), k = bid/8, r = k%REP (pair-block), m = k/REP,
// chunk = u + 8*m). All REP replicas of a chunk differ by a multiple of 8 in bid
// -> same XCD -> the chunk's 19.2/4.8 KB stays in that XCD's L2 for all replicas.
template<int NCH>
__global__ void sim5_kernel(const float* __restrict__ pnorm,
                            const float* __restrict__ snorm,
                            float* __restrict__ pval, int* __restrict__ pidx)
{
    constexpr int CS = N_ / NCH;   // songs per chunk
    constexpr int NG = CS / 4;     // 4-song groups per chunk
    const int bid = blockIdx.x;
    const int u = bid & 7;
    const int k = bid >> 3;
    const int r = k % REP;
    const int m = k / REP;
    const int chunk = u + 8 * m;
    if (chunk >= NCH) return;      // padding block (when NCH % 8 != 0)

    const int t = threadIdx.x;
    const int j0 = r * (2 * TPB) + t;
    const int j1 = j0 + TPB;

    float qa[D_], qb[D_];
#pragma unroll
    for (int d = 0; d < D_; ++d) qa[d] = pnorm[j0 * DP_ + d];
#pragma unroll
    for (int d = 0; d < D_; ++d) qb[d] = pnorm[j1 * DP_ + d];

    float bva = -1e30f, bvb = -1e30f;
    int   ga = 0, gb = 0;

    const float4* s4 = reinterpret_cast<const float4*>(snorm) + (size_t)chunk * CS * 3;

#pragma unroll 2
    for (int g = 0; g < NG; ++g) {
        float4 v[12];
#pragma unroll
        for (int kk = 0; kk < 12; ++kk) v[kk] = s4[g * 12 + kk];
        float a0 = dot11(qa, v[0], v[1],  v[2]);
        float a1 = dot11(qa, v[3], v[4],  v[5]);
        float a2 = dot11(qa, v[6], v[7],  v[8]);
        float a3 = dot11(qa, v[9], v[10], v[11]);
        float b0 = dot11(qb, v[0], v[1],  v[2]);
        float b1 = dot11(qb, v[3], v[4],  v[5]);
        float b2 = dot11(qb, v[6], v[7],  v[8]);
        float b3 = dot11(qb, v[9], v[10], v[11]);
        float ma = fmaxf(fmaxf(a0, a1), fmaxf(a2, a3));   // fuses to v_max3+v_max
        float mb = fmaxf(fmaxf(b0, b1), fmaxf(b2, b3));
        // strictly-greater keeps FIRST group: numpy first-index argmax semantics
        if (ma > bva) { bva = ma; ga = g; }
        if (mb > bvb) { bvb = mb; gb = g; }
    }

    // Recompute winning group with the identical fmaf sequence -> bit-exact;
    // descending scan picks the FIRST in-group index achieving the max.
    int ia, ib;
    {
        const float4* vg = s4 + (size_t)ga * 12;
        float4 w[12];
#pragma unroll
        for (int kk = 0; kk < 12; ++kk) w[kk] = vg[kk];
        float a0 = dot11(qa, w[0], w[1],  w[2]);
        float a1 = dot11(qa, w[3], w[4],  w[5]);
        float a2 = dot11(qa, w[6], w[7],  w[8]);
        float a3 = dot11(qa, w[9], w[10], w[11]);
        int base = chunk * CS + ga * 4;
        ia = base;
        if (a3 == bva) ia = base + 3;
        if (a2 == bva) ia = base + 2;
        if (a1 == bva) ia = base + 1;
        if (a0 == bva) ia = base;
    }
    {
        const float4* vg = s4 + (size_t)gb * 12;
        float4 w[12];
#pragma unroll
        for (int kk = 0; kk < 12; ++kk) w[kk] = vg[kk];
        float b0 = dot11(qb, w[0], w[1],  w[2]);
        float b1 = dot11(qb, w[3], w[4],  w[5]);
        float b2 = dot11(qb, w[6], w[7],  w[8]);
        float b3 = dot11(qb, w[9], w[10], w[11]);
        int base = chunk * CS + gb * 4;
        ib = base;
        if (b3 == bvb) ib = base + 3;
        if (b2 == bvb) ib = base + 2;
        if (b1 == bvb) ib = base + 1;
        if (b0 == bvb) ib = base;
    }

    // [chunk][pair] layout: adjacent lanes -> adjacent addresses (full lines)
    pval[(size_t)chunk * NPAIR + j0] = bva;
    pidx[(size_t)chunk * NPAIR + j0] = ia;
    pval[(size_t)chunk * NPAIR + j1] = bvb;
    pidx[(size_t)chunk * NPAIR + j1] = ib;
}

// ---------------- fallback (no snorm workspace): normalize on the fly ------------
template<int NCH>
__global__ void sim2f_kernel(const float* __restrict__ pnorm,
                             const float* __restrict__ songs,
                             float* __restrict__ pval, int* __restrict__ pidx)
{
    constexpr int CS = N_ / NCH;
    const int chunk = blockIdx.x;
    const int j = blockIdx.y * TPB + threadIdx.x;

    float qv[D_];
#pragma unroll
    for (int d = 0; d < D_; ++d) qv[d] = pnorm[j * DP_ + d];

    float bestv = -1e30f;
    int   besti = 0;
    const int base = chunk * CS;
    for (int i = base; i < base + CS; ++i) {
        float sv[D_]; float ss = 0.0f;
#pragma unroll
        for (int d = 0; d < D_; ++d) { sv[d] = songs[(size_t)i * D_ + d]; ss += sv[d] * sv[d]; }
        float nrm = fmaxf(sqrtf(ss), EPS);
        float a = qv[0] * (sv[0] / nrm);
#pragma unroll
        for (int d = 1; d < D_; ++d) a = fmaf(qv[d], sv[d] / nrm, a);
        if (a > bestv) { bestv = a; besti = i; }
    }
    pval[(size_t)chunk * NPAIR + j] = bestv;
    pidx[(size_t)chunk * NPAIR + j] = besti;
}

// ---------------- final reduce over chunks + gather: one wave per pair ------------
template<int NCH>
__global__ void final2_kernel(const float* __restrict__ pval, const int* __restrict__ pidx,
                              const float* __restrict__ songs, float* __restrict__ out)
{
    const int pair = blockIdx.x * 4 + (threadIdx.x >> 6);
    const int lane = threadIdx.x & 63;
    float v = -1e30f; int ix = 0x7fffffff;
#pragma unroll
    for (int k = 0; k < (NCH + 63) / 64; ++k) {
        int c = lane + k * 64;
        if (c < NCH) {
            float v2 = pval[(size_t)c * NPAIR + pair];
            int   i2 = pidx[(size_t)c * NPAIR + pair];
            if (v2 > v || (v2 == v && i2 < ix)) { v = v2; ix = i2; }
        }
    }
#pragma unroll
    for (int off = 1; off < 64; off <<= 1) {
        float v2 = __shfl_xor(v, off, 64);
        int   i2 = __shfl_xor(ix, off, 64);
        if (v2 > v || (v2 == v && i2 < ix)) { v = v2; ix = i2; }
    }
    if (lane < D_) out[(size_t)pair * D_ + lane] = songs[(size_t)ix * D_ + lane];
}

extern "C" void kernel_launch(void* const* d_in, const int* in_sizes, int n_in,
                              void* d_out, int out_size, void* d_ws, size_t ws_size,
                              hipStream_t stream)
{
    const float* x     = (const float*)d_in[0];
    const float* W1    = (const float*)d_in[1];
    const float* b1    = (const float*)d_in[2];
    const float* W2    = (const float*)d_in[3];
    const float* b2    = (const float*)d_in[4];
    const float* W3    = (const float*)d_in[5];
    const float* b3    = (const float*)d_in[6];
    const float* songs = (const float*)d_in[7];
    float* out = (float*)d_out;

    float* pnorm = (float*)d_ws;                            // NPAIR*DP floats
    constexpr size_t PN = (size_t)NPAIR * DP_;
    constexpr size_t SN = (size_t)N_ * DP_;
    constexpr int SNB = (N_ + 255) / 256;                   // snorm blocks

    auto need = [](int nch) {
        return (PN + SN + 2ull * NPAIR * nch) * sizeof(float);
    };

    if (ws_size >= need(1000)) {
        constexpr int NCH = 1000;                           // CS=100, grid 5000 (no padding)
        float* snorm = pnorm + PN;
        float* pval  = snorm + SN;
        int*   pidx  = (int*)(pval + (size_t)NPAIR * NCH);
        prep_kernel<<<B_ + SNB, 256, 0, stream>>>(x, W1, b1, W2, b2, W3, b3, songs,
                                                  pnorm, snorm, 1);
        constexpr int GRID = 8 * ((NCH + 7) / 8) * REP;
        sim5_kernel<NCH><<<GRID, TPB, 0, stream>>>(pnorm, snorm, pval, pidx);
        final2_kernel<NCH><<<NPAIR / 4, 256, 0, stream>>>(pval, pidx, songs, out);
    } else if (ws_size >= need(250)) {
        constexpr int NCH = 250;                            // CS=400, grid padded to 1280
        float* snorm = pnorm + PN;
        float* pval  = snorm + SN;
        int*   pidx  = (int*)(pval + (size_t)NPAIR * NCH);
        prep_kernel<<<B_ + SNB, 256, 0, stream>>>(x, W1, b1, W2, b2, W3, b3, songs,
                                                  pnorm, snorm, 1);
        constexpr int GRID = 8 * ((NCH + 7) / 8) * REP;
        sim5_kernel<NCH><<<GRID, TPB, 0, stream>>>(pnorm, snorm, pval, pidx);
        final2_kernel<NCH><<<NPAIR / 4, 256, 0, stream>>>(pval, pidx, songs, out);
    } else if (ws_size >= (PN + 2ull * NPAIR * 250) * sizeof(float)) {
        constexpr int NCH = 250;
        float* pval = pnorm + PN;
        int*   pidx = (int*)(pval + (size_t)NPAIR * NCH);
        prep_kernel<<<B_, 256, 0, stream>>>(x, W1, b1, W2, b2, W3, b3, songs,
                                            pnorm, nullptr, 0);
        sim2f_kernel<NCH><<<dim3(NCH, NPAIR / TPB), TPB, 0, stream>>>(pnorm, songs, pval, pidx);
        final2_kernel<NCH><<<NPAIR / 4, 256, 0, stream>>>(pval, pidx, songs, out);
    } else {
        constexpr int NCH = 50;
        float* pval = pnorm + PN;
        int*   pidx = (int*)(pval + (size_t)NPAIR * NCH);
        prep_kernel<<<B_, 256, 0, stream>>>(x, W1, b1, W2, b2, W3, b3, songs,
                                            pnorm, nullptr, 0);
        sim2f_kernel<NCH><<<dim3(NCH, NPAIR / TPB), TPB, 0, stream>>>(pnorm, songs, pval, pidx);
        final2_kernel<NCH><<<NPAIR / 4, 256, 0, stream>>>(pval, pidx, songs, out);
    }
}

// Round 6
// 103.922 us; speedup vs baseline: 1.8471x; 1.4028x over previous
//
#include <hip/hip_runtime.h>
#include <math.h>

#define EPS 1e-8f

constexpr int B_ = 128;     // batch
constexpr int Q_ = 20;      // queries per sample
constexpr int D_ = 11;      // feature dim
constexpr int N_ = 100000;  // songs
constexpr int DP_ = 12;     // padded feature dim (3x float4)
constexpr int NPAIR = B_ * Q_;  // 2560
constexpr int TPB = 256;
constexpr int REP = NPAIR / (2 * TPB);  // 5 pair-blocks (2 pairs per thread)
constexpr int NCH = 1000;   // song chunks (divisible by 8 -> clean XCD swizzle)
constexpr int CS = N_ / NCH;   // 100 songs per chunk
constexpr int NG = CS / 4;     // 25 4-song groups per chunk

// ---------------- fused prep: MLP encoder + song pre-normalization ---------------
__global__ void prep_kernel(const float* __restrict__ x,
                            const float* __restrict__ W1, const float* __restrict__ b1,
                            const float* __restrict__ W2, const float* __restrict__ b2,
                            const float* __restrict__ W3, const float* __restrict__ b3,
                            const float* __restrict__ songs,
                            float* __restrict__ pnorm, float* __restrict__ snorm,
                            int do_snorm)
{
    const int t = threadIdx.x;
    if (blockIdx.x >= B_) {
        if (!do_snorm) return;
        const int i = (blockIdx.x - B_) * blockDim.x + t;
        if (i >= N_) return;
        float v[DP_]; float ss = 0.0f;
#pragma unroll
        for (int d = 0; d < D_; ++d) { v[d] = songs[(size_t)i * D_ + d]; ss += v[d] * v[d]; }
        float nrm = fmaxf(sqrtf(ss), EPS);
#pragma unroll
        for (int d = 0; d < D_; ++d) v[d] /= nrm;
        v[D_] = 0.0f;
        float4* o = reinterpret_cast<float4*>(snorm + (size_t)i * DP_);
        o[0] = make_float4(v[0], v[1], v[2], v[3]);
        o[1] = make_float4(v[4], v[5], v[6], v[7]);
        o[2] = make_float4(v[8], v[9], v[10], v[11]);
        return;
    }
    __shared__ float xr[55];
    __shared__ float h1[128];
    __shared__ float h2[64];
    __shared__ float prod[220];
    const int b = blockIdx.x;
    if (t < 55) xr[t] = x[b * 55 + t];
    __syncthreads();
    if (t < 128) {
        float s = b1[t];
        for (int k = 0; k < 55; ++k) s += xr[k] * W1[k * 128 + t];
        h1[t] = fmaxf(s, 0.0f);
    }
    __syncthreads();
    if (t < 64) {
        float s = b2[t];
        for (int k = 0; k < 128; ++k) s += h1[k] * W2[k * 64 + t];
        h2[t] = fmaxf(s, 0.0f);
    }
    __syncthreads();
    if (t < 220) {
        float s = b3[t];
        for (int k = 0; k < 64; ++k) s += h2[k] * W3[k * 220 + t];
        prod[t] = s;
    }
    __syncthreads();
    if (t < Q_) {
        float ss = 0.0f;
        for (int d = 0; d < D_; ++d) { float v = prod[t * D_ + d]; ss += v * v; }
        float nrm = fmaxf(sqrtf(ss), EPS);
        float* o = pnorm + (b * Q_ + t) * DP_;
        for (int d = 0; d < D_; ++d) o[d] = prod[t * D_ + d] / nrm;
        o[D_] = 0.0f;
    }
}

// dot over 11 dims, fixed fmaf sequence (deterministic, identical at every call site)
__device__ __forceinline__ float dot11(const float* __restrict__ q,
                                       const float4 a, const float4 b, const float4 c)
{
    float x = q[0] * a.x;
    x = fmaf(q[1], a.y, x);
    x = fmaf(q[2], a.z, x);
    x = fmaf(q[3], a.w, x);
    x = fmaf(q[4], b.x, x);
    x = fmaf(q[5], b.y, x);
    x = fmaf(q[6], b.z, x);
    x = fmaf(q[7], b.w, x);
    x = fmaf(q[8], c.x, x);
    x = fmaf(q[9], c.y, x);
    x = fmaf(q[10], c.z, x);
    return x;
}

// monotone float -> uint32 (strictly order-preserving for non-NaN)
__device__ __forceinline__ unsigned int fkey(float f)
{
    unsigned int b = __float_as_uint(f);
    return (b & 0x80000000u) ? ~b : (b | 0x80000000u);
}

// pack (value, index): high = monotone value, low = ~idx so that for equal values
// atomicMax keeps the SMALLER index (numpy first-index argmax semantics)
__device__ __forceinline__ unsigned long long pack_vi(float v, int idx)
{
    return ((unsigned long long)fkey(v) << 32) | (unsigned long long)(0xFFFFFFFFu - (unsigned int)idx);
}

// ---------------- sim + global argmax via packed atomicMax ------------------------
// XCD-swizzled 1-D grid: bid -> (u=bid&7 fixed XCD, r=pair-block, chunk=u+8*m).
// Chunk staged in LDS once per block; group loop reads uniform-address
// ds_read_b128 (broadcast, conflict-free). Wave-staggered group order with
// explicit min-group tie-break preserves exact first-index semantics.
__global__ __launch_bounds__(TPB, 4)
void sim6_kernel(const float* __restrict__ pnorm,
                 const float* __restrict__ snorm,
                 unsigned long long* __restrict__ res)
{
    __shared__ __align__(16) float lds[CS * DP_];   // 4800 B
    const int bid = blockIdx.x;
    const int u = bid & 7;
    const int k = bid >> 3;
    const int r = k % REP;
    const int m = k / REP;
    const int chunk = u + 8 * m;                    // NCH % 8 == 0 -> no padding
    const int t = threadIdx.x;

    // stage chunk: CS*3 float4s, coalesced
    const float4* src = reinterpret_cast<const float4*>(snorm) + (size_t)chunk * CS * 3;
    float4* l4 = reinterpret_cast<float4*>(lds);
    for (int i = t; i < CS * 3; i += TPB) l4[i] = src[i];

    const int j0 = r * (2 * TPB) + t;
    const int j1 = j0 + TPB;
    float qa[D_], qb[D_];
#pragma unroll
    for (int d = 0; d < D_; ++d) qa[d] = pnorm[j0 * DP_ + d];
#pragma unroll
    for (int d = 0; d < D_; ++d) qb[d] = pnorm[j1 * DP_ + d];
    __syncthreads();

    float bva = -1e30f, bvb = -1e30f;
    int   ga = 0, gb = 0;

    // wave-staggered group order (decorrelates LDS/latency bursts across waves)
    int g = ((t >> 6) * 6) % NG;
    for (int it = 0; it < NG; ++it) {
        const float4* vg = l4 + g * 12;
        // two songs, then two songs: keeps live float4 count at 6 (low VGPR)
        float4 v0 = vg[0], v1 = vg[1], v2 = vg[2], v3 = vg[3], v4 = vg[4], v5 = vg[5];
        float a0 = dot11(qa, v0, v1, v2);
        float a1 = dot11(qa, v3, v4, v5);
        float b0 = dot11(qb, v0, v1, v2);
        float b1 = dot11(qb, v3, v4, v5);
        float4 w0 = vg[6], w1 = vg[7], w2 = vg[8], w3 = vg[9], w4 = vg[10], w5 = vg[11];
        float a2 = dot11(qa, w0, w1, w2);
        float a3 = dot11(qa, w3, w4, w5);
        float b2 = dot11(qb, w0, w1, w2);
        float b3 = dot11(qb, w3, w4, w5);
        float ma = fmaxf(fmaxf(a0, a1), fmaxf(a2, a3));
        float mb = fmaxf(fmaxf(b0, b1), fmaxf(b2, b3));
        // strictly-greater OR (equal AND smaller group): global first-index under stagger
        if (ma > bva || (ma == bva && g < ga)) { bva = ma; ga = g; }
        if (mb > bvb || (mb == bvb && g < gb)) { bvb = mb; gb = g; }
        if (++g == NG) g = 0;
    }

    // Recompute winning group with the identical fmaf sequence -> bit-exact;
    // descending cascade picks the FIRST in-group index achieving the max.
    {
        const float4* vg = l4 + ga * 12;
        float a0 = dot11(qa, vg[0], vg[1],  vg[2]);
        float a1 = dot11(qa, vg[3], vg[4],  vg[5]);
        float a2 = dot11(qa, vg[6], vg[7],  vg[8]);
        float a3 = dot11(qa, vg[9], vg[10], vg[11]);
        int base = chunk * CS + ga * 4;
        int ia = base;
        if (a3 == bva) ia = base + 3;
        if (a2 == bva) ia = base + 2;
        if (a1 == bva) ia = base + 1;
        if (a0 == bva) ia = base;
        atomicMax(&res[j0], pack_vi(bva, ia));
    }
    {
        const float4* vg = l4 + gb * 12;
        float b0 = dot11(qb, vg[0], vg[1],  vg[2]);
        float b1 = dot11(qb, vg[3], vg[4],  vg[5]);
        float b2 = dot11(qb, vg[6], vg[7],  vg[8]);
        float b3 = dot11(qb, vg[9], vg[10], vg[11]);
        int base = chunk * CS + gb * 4;
        int ib = base;
        if (b3 == bvb) ib = base + 3;
        if (b2 == bvb) ib = base + 2;
        if (b1 == bvb) ib = base + 1;
        if (b0 == bvb) ib = base;
        atomicMax(&res[j1], pack_vi(bvb, ib));
    }
}

// ---------------- fallback (no snorm workspace): global loads, on-the-fly norm ----
template<int FNCH>
__global__ void sim6f_kernel(const float* __restrict__ pnorm,
                             const float* __restrict__ songs,
                             unsigned long long* __restrict__ res)
{
    constexpr int FCS = N_ / FNCH;
    const int chunk = blockIdx.x;
    const int j = blockIdx.y * TPB + threadIdx.x;

    float qv[D_];
#pragma unroll
    for (int d = 0; d < D_; ++d) qv[d] = pnorm[j * DP_ + d];

    float bestv = -1e30f;
    int   besti = 0;
    const int base = chunk * FCS;
    for (int i = base; i < base + FCS; ++i) {
        float sv[D_]; float ss = 0.0f;
#pragma unroll
        for (int d = 0; d < D_; ++d) { sv[d] = songs[(size_t)i * D_ + d]; ss += sv[d] * sv[d]; }
        float nrm = fmaxf(sqrtf(ss), EPS);
        float a = qv[0] * (sv[0] / nrm);
#pragma unroll
        for (int d = 1; d < D_; ++d) a = fmaf(qv[d], sv[d] / nrm, a);
        if (a > bestv) { bestv = a; besti = i; }
    }
    atomicMax(&res[j], pack_vi(bestv, besti));
}

// ---------------- decode + gather ------------------------------------------------
__global__ void gather_kernel(const unsigned long long* __restrict__ res,
                              const float* __restrict__ songs, float* __restrict__ out)
{
    const int j = blockIdx.x * blockDim.x + threadIdx.x;
    if (j >= NPAIR) return;
    const unsigned int idx = 0xFFFFFFFFu - (unsigned int)(res[j] & 0xFFFFFFFFull);
#pragma unroll
    for (int d = 0; d < D_; ++d) out[(size_t)j * D_ + d] = songs[(size_t)idx * D_ + d];
}

extern "C" void kernel_launch(void* const* d_in, const int* in_sizes, int n_in,
                              void* d_out, int out_size, void* d_ws, size_t ws_size,
                              hipStream_t stream)
{
    const float* x     = (const float*)d_in[0];
    const float* W1    = (const float*)d_in[1];
    const float* b1    = (const float*)d_in[2];
    const float* W2    = (const float*)d_in[3];
    const float* b2    = (const float*)d_in[4];
    const float* W3    = (const float*)d_in[5];
    const float* b3    = (const float*)d_in[6];
    const float* songs = (const float*)d_in[7];
    float* out = (float*)d_out;

    constexpr size_t PN = (size_t)NPAIR * DP_;      // pnorm floats
    constexpr size_t SN = (size_t)N_ * DP_;         // snorm floats
    float* pnorm = (float*)d_ws;
    constexpr int SNB = (N_ + 255) / 256;

    const size_t need_full = (PN + SN) * sizeof(float) + (size_t)NPAIR * 8 + 64;
    const size_t need_min  = PN * sizeof(float) + (size_t)NPAIR * 8 + 64;

    if (ws_size >= need_full) {
        float* snorm = pnorm + PN;
        // align res to 8 bytes
        unsigned long long* res =
            (unsigned long long*)(((uintptr_t)(snorm + SN) + 7) & ~(uintptr_t)7);
        hipMemsetAsync(res, 0, (size_t)NPAIR * 8, stream);
        prep_kernel<<<B_ + SNB, 256, 0, stream>>>(x, W1, b1, W2, b2, W3, b3, songs,
                                                  pnorm, snorm, 1);
        sim6_kernel<<<NCH * REP, TPB, 0, stream>>>(pnorm, snorm, res);
        gather_kernel<<<(NPAIR + 255) / 256, 256, 0, stream>>>(res, songs, out);
    } else if (ws_size >= need_min) {
        unsigned long long* res =
            (unsigned long long*)(((uintptr_t)(pnorm + PN) + 7) & ~(uintptr_t)7);
        hipMemsetAsync(res, 0, (size_t)NPAIR * 8, stream);
        prep_kernel<<<B_, 256, 0, stream>>>(x, W1, b1, W2, b2, W3, b3, songs,
                                            pnorm, nullptr, 0);
        constexpr int FNCH = 250;
        sim6f_kernel<FNCH><<<dim3(FNCH, NPAIR / TPB), TPB, 0, stream>>>(pnorm, songs, res);
        gather_kernel<<<(NPAIR + 255) / 256, 256, 0, stream>>>(res, songs, out);
    }
}

// Round 7
// 92.782 us; speedup vs baseline: 2.0689x; 1.1201x over previous
//
#include <hip/hip_runtime.h>
#include <math.h>

#define EPS 1e-8f

constexpr int B_ = 128;     // batch
constexpr int Q_ = 20;      // queries per sample
constexpr int D_ = 11;      // feature dim
constexpr int N_ = 100000;  // songs
constexpr int DP_ = 12;     // padded feature dim (3x float4)
constexpr int NPAIR = B_ * Q_;  // 2560
constexpr int NCH = 1000;   // song chunks (divisible by 8 -> clean XCD swizzle)
constexpr int CS = N_ / NCH;   // 100 songs per chunk
constexpr int NG = CS / 4;     // 25 4-song groups per chunk
constexpr int STPB = 128;   // sim block size
constexpr int PPT = 4;      // pairs per thread
constexpr int REP = NPAIR / (PPT * STPB);  // 5 pair-blocks

// ---------------- fused prep: MLP encoder + song pre-normalization ---------------
__global__ void prep_kernel(const float* __restrict__ x,
                            const float* __restrict__ W1, const float* __restrict__ b1,
                            const float* __restrict__ W2, const float* __restrict__ b2,
                            const float* __restrict__ W3, const float* __restrict__ b3,
                            const float* __restrict__ songs,
                            float* __restrict__ pnorm, float* __restrict__ snorm,
                            int do_snorm)
{
    const int t = threadIdx.x;
    if (blockIdx.x >= B_) {
        if (!do_snorm) return;
        const int i = (blockIdx.x - B_) * blockDim.x + t;
        if (i >= N_) return;
        float v[DP_]; float ss = 0.0f;
#pragma unroll
        for (int d = 0; d < D_; ++d) { v[d] = songs[(size_t)i * D_ + d]; ss += v[d] * v[d]; }
        float nrm = fmaxf(sqrtf(ss), EPS);
#pragma unroll
        for (int d = 0; d < D_; ++d) v[d] /= nrm;
        v[D_] = 0.0f;
        float4* o = reinterpret_cast<float4*>(snorm + (size_t)i * DP_);
        o[0] = make_float4(v[0], v[1], v[2], v[3]);
        o[1] = make_float4(v[4], v[5], v[6], v[7]);
        o[2] = make_float4(v[8], v[9], v[10], v[11]);
        return;
    }
    __shared__ float xr[55];
    __shared__ float h1[128];
    __shared__ float h2[64];
    __shared__ float prod[220];
    const int b = blockIdx.x;
    if (t < 55) xr[t] = x[b * 55 + t];
    __syncthreads();
    if (t < 128) {
        float s = b1[t];
        for (int k = 0; k < 55; ++k) s += xr[k] * W1[k * 128 + t];
        h1[t] = fmaxf(s, 0.0f);
    }
    __syncthreads();
    if (t < 64) {
        float s = b2[t];
        for (int k = 0; k < 128; ++k) s += h1[k] * W2[k * 64 + t];
        h2[t] = fmaxf(s, 0.0f);
    }
    __syncthreads();
    if (t < 220) {
        float s = b3[t];
        for (int k = 0; k < 64; ++k) s += h2[k] * W3[k * 220 + t];
        prod[t] = s;
    }
    __syncthreads();
    if (t < Q_) {
        float ss = 0.0f;
        for (int d = 0; d < D_; ++d) { float v = prod[t * D_ + d]; ss += v * v; }
        float nrm = fmaxf(sqrtf(ss), EPS);
        float* o = pnorm + (b * Q_ + t) * DP_;
        for (int d = 0; d < D_; ++d) o[d] = prod[t * D_ + d] / nrm;
        o[D_] = 0.0f;
    }
}

// dot over 11 dims, fixed fmaf sequence (deterministic, identical at every call site)
__device__ __forceinline__ float dot11(const float* __restrict__ q,
                                       const float4 a, const float4 b, const float4 c)
{
    float x = q[0] * a.x;
    x = fmaf(q[1], a.y, x);
    x = fmaf(q[2], a.z, x);
    x = fmaf(q[3], a.w, x);
    x = fmaf(q[4], b.x, x);
    x = fmaf(q[5], b.y, x);
    x = fmaf(q[6], b.z, x);
    x = fmaf(q[7], b.w, x);
    x = fmaf(q[8], c.x, x);
    x = fmaf(q[9], c.y, x);
    x = fmaf(q[10], c.z, x);
    return x;
}

// monotone float -> uint32 (strictly order-preserving for non-NaN)
__device__ __forceinline__ unsigned int fkey(float f)
{
    unsigned int b = __float_as_uint(f);
    return (b & 0x80000000u) ? ~b : (b | 0x80000000u);
}

// pack (value, index): high = monotone value, low = ~idx so that for equal values
// atomicMax keeps the SMALLER index (numpy first-index argmax semantics)
__device__ __forceinline__ unsigned long long pack_vi(float v, int idx)
{
    return ((unsigned long long)fkey(v) << 32) | (unsigned long long)(0xFFFFFFFFu - (unsigned int)idx);
}

// ---------------- sim + global argmax: 4 pairs/thread, LDS chunk, atomicMax -------
// XCD-swizzled 1-D grid: bid -> (u=bid&7 fixed XCD, r=pair-block, chunk=u+8*m).
// Chunk staged in LDS once per block; group loop reads wave-uniform ds_read_b128
// (broadcast). 176 FMA per 12 LDS reads (PPT=4).
__global__ __launch_bounds__(STPB, 4)
void sim7_kernel(const float* __restrict__ pnorm,
                 const float* __restrict__ snorm,
                 unsigned long long* __restrict__ res)
{
    __shared__ __align__(16) float lds[CS * DP_];   // 4800 B
    const int bid = blockIdx.x;
    const int u = bid & 7;
    const int k = bid >> 3;
    const int r = k % REP;
    const int m = k / REP;
    const int chunk = u + 8 * m;                    // NCH % 8 == 0 -> no padding
    const int t = threadIdx.x;

    // stage chunk: CS*3 float4s, coalesced
    const float4* src = reinterpret_cast<const float4*>(snorm) + (size_t)chunk * CS * 3;
    float4* l4 = reinterpret_cast<float4*>(lds);
    for (int i = t; i < CS * 3; i += STPB) l4[i] = src[i];

    const int jb = r * (PPT * STPB) + t;
    float qv[PPT][D_];
#pragma unroll
    for (int p = 0; p < PPT; ++p) {
        const float4* q4 = reinterpret_cast<const float4*>(pnorm + (size_t)(jb + p * STPB) * DP_);
        float4 qa = q4[0], qb = q4[1], qc = q4[2];
        qv[p][0] = qa.x; qv[p][1] = qa.y; qv[p][2]  = qa.z; qv[p][3] = qa.w;
        qv[p][4] = qb.x; qv[p][5] = qb.y; qv[p][6]  = qb.z; qv[p][7] = qb.w;
        qv[p][8] = qc.x; qv[p][9] = qc.y; qv[p][10] = qc.z;
    }
    __syncthreads();

    float bv[PPT]; int gi[PPT];
#pragma unroll
    for (int p = 0; p < PPT; ++p) { bv[p] = -1e30f; gi[p] = 0; }

    const float4* vg = l4;
    for (int g = 0; g < NG; ++g, vg += 12) {
        // songs 0,1 of the group (6 live float4s)
        float4 v0 = vg[0], v1 = vg[1], v2 = vg[2], v3 = vg[3], v4 = vg[4], v5 = vg[5];
        float a0[PPT], a1[PPT];
#pragma unroll
        for (int p = 0; p < PPT; ++p) {
            a0[p] = dot11(qv[p], v0, v1, v2);
            a1[p] = dot11(qv[p], v3, v4, v5);
        }
        // songs 2,3
        float4 w0 = vg[6], w1 = vg[7], w2 = vg[8], w3 = vg[9], w4 = vg[10], w5 = vg[11];
#pragma unroll
        for (int p = 0; p < PPT; ++p) {
            float a2 = dot11(qv[p], w0, w1, w2);
            float a3 = dot11(qv[p], w3, w4, w5);
            float mx = fmaxf(fmaxf(a0[p], a1[p]), fmaxf(a2, a3));  // v_max3 + v_max
            // strictly-greater keeps FIRST group: numpy first-index argmax semantics
            if (mx > bv[p]) { bv[p] = mx; gi[p] = g; }
        }
    }

    // Recompute winning group with the identical fmaf sequence -> bit-exact;
    // descending cascade picks the FIRST in-group index achieving the max.
#pragma unroll
    for (int p = 0; p < PPT; ++p) {
        const float4* wg = l4 + gi[p] * 12;
        float a0 = dot11(qv[p], wg[0], wg[1],  wg[2]);
        float a1 = dot11(qv[p], wg[3], wg[4],  wg[5]);
        float a2 = dot11(qv[p], wg[6], wg[7],  wg[8]);
        float a3 = dot11(qv[p], wg[9], wg[10], wg[11]);
        int base = chunk * CS + gi[p] * 4;
        int idx = base;
        if (a3 == bv[p]) idx = base + 3;
        if (a2 == bv[p]) idx = base + 2;
        if (a1 == bv[p]) idx = base + 1;
        if (a0 == bv[p]) idx = base;
        atomicMax(&res[jb + p * STPB], pack_vi(bv[p], idx));
    }
}

// ---------------- fallback (no snorm workspace): global loads, on-the-fly norm ----
template<int FNCH>
__global__ void sim6f_kernel(const float* __restrict__ pnorm,
                             const float* __restrict__ songs,
                             unsigned long long* __restrict__ res)
{
    constexpr int FCS = N_ / FNCH;
    const int chunk = blockIdx.x;
    const int j = blockIdx.y * 256 + threadIdx.x;

    float qv[D_];
#pragma unroll
    for (int d = 0; d < D_; ++d) qv[d] = pnorm[j * DP_ + d];

    float bestv = -1e30f;
    int   besti = 0;
    const int base = chunk * FCS;
    for (int i = base; i < base + FCS; ++i) {
        float sv[D_]; float ss = 0.0f;
#pragma unroll
        for (int d = 0; d < D_; ++d) { sv[d] = songs[(size_t)i * D_ + d]; ss += sv[d] * sv[d]; }
        float nrm = fmaxf(sqrtf(ss), EPS);
        float a = qv[0] * (sv[0] / nrm);
#pragma unroll
        for (int d = 1; d < D_; ++d) a = fmaf(qv[d], sv[d] / nrm, a);
        if (a > bestv) { bestv = a; besti = i; }
    }
    atomicMax(&res[j], pack_vi(bestv, besti));
}

// ---------------- decode + gather ------------------------------------------------
__global__ void gather_kernel(const unsigned long long* __restrict__ res,
                              const float* __restrict__ songs, float* __restrict__ out)
{
    const int j = blockIdx.x * blockDim.x + threadIdx.x;
    if (j >= NPAIR) return;
    const unsigned int idx = 0xFFFFFFFFu - (unsigned int)(res[j] & 0xFFFFFFFFull);
#pragma unroll
    for (int d = 0; d < D_; ++d) out[(size_t)j * D_ + d] = songs[(size_t)idx * D_ + d];
}

extern "C" void kernel_launch(void* const* d_in, const int* in_sizes, int n_in,
                              void* d_out, int out_size, void* d_ws, size_t ws_size,
                              hipStream_t stream)
{
    const float* x     = (const float*)d_in[0];
    const float* W1    = (const float*)d_in[1];
    const float* b1    = (const float*)d_in[2];
    const float* W2    = (const float*)d_in[3];
    const float* b2    = (const float*)d_in[4];
    const float* W3    = (const float*)d_in[5];
    const float* b3    = (const float*)d_in[6];
    const float* songs = (const float*)d_in[7];
    float* out = (float*)d_out;

    constexpr size_t PN = (size_t)NPAIR * DP_;      // pnorm floats
    constexpr size_t SN = (size_t)N_ * DP_;         // snorm floats
    float* pnorm = (float*)d_ws;
    constexpr int SNB = (N_ + 255) / 256;

    const size_t need_full = (PN + SN) * sizeof(float) + (size_t)NPAIR * 8 + 64;
    const size_t need_min  = PN * sizeof(float) + (size_t)NPAIR * 8 + 64;

    if (ws_size >= need_full) {
        float* snorm = pnorm + PN;
        unsigned long long* res =
            (unsigned long long*)(((uintptr_t)(snorm + SN) + 7) & ~(uintptr_t)7);
        hipMemsetAsync(res, 0, (size_t)NPAIR * 8, stream);
        prep_kernel<<<B_ + SNB, 256, 0, stream>>>(x, W1, b1, W2, b2, W3, b3, songs,
                                                  pnorm, snorm, 1);
        sim7_kernel<<<NCH * REP, STPB, 0, stream>>>(pnorm, snorm, res);
        gather_kernel<<<(NPAIR + 255) / 256, 256, 0, stream>>>(res, songs, out);
    } else if (ws_size >= need_min) {
        unsigned long long* res =
            (unsigned long long*)(((uintptr_t)(pnorm + PN) + 7) & ~(uintptr_t)7);
        hipMemsetAsync(res, 0, (size_t)NPAIR * 8, stream);
        prep_kernel<<<B_, 256, 0, stream>>>(x, W1, b1, W2, b2, W3, b3, songs,
                                            pnorm, nullptr, 0);
        constexpr int FNCH = 250;
        sim6f_kernel<FNCH><<<dim3(FNCH, NPAIR / 256), 256, 0, stream>>>(pnorm, songs, res);
        gather_kernel<<<(NPAIR + 255) / 256, 256, 0, stream>>>(res, songs, out);
    }
}